// Round 3
// baseline (330.800 us; speedup 1.0000x reference)
//
#include <hip/hip_runtime.h>
#include <stdint.h>

typedef _Float16 f16;
typedef _Float16 f16x8 __attribute__((ext_vector_type(8)));
typedef _Float16 f16x4 __attribute__((ext_vector_type(4)));
typedef float floatx4 __attribute__((ext_vector_type(4)));
typedef float floatx2 __attribute__((ext_vector_type(2)));

#define TT 64
#define CDIM 384
#define HH 64
#define NKK 12          // CDIM/32 k-steps
#define LDP 72          // f16 LDS row stride (144 B: 16B-aligned, conflict-benign)
#define OST 66          // fp32 O-staging row stride
#define ARENA 4608      // f16 elements per tail arena (64*LDP)
#define SCALE 0.05103103630798288f   // 384^-0.5 (reference scales by C^-0.5)

// Pre-pass: Wq/Wk/Wv -> fp16 in exact MFMA B-fragment order:
// wf layout [kk][p][tile][lane] of f16x8; lane holds W[k=kk*32+quad*8+j][n=tile*16+(lane&15)]
__global__ void prep_w(const float* __restrict__ Wq,
                       const float* __restrict__ Wk,
                       const float* __restrict__ Wv,
                       f16* __restrict__ wf) {
    int t = blockIdx.x * 256 + threadIdx.x;
    if (t >= 3 * NKK * 4 * 64) return;
    int lane = t & 63;
    int tile = (t >> 6) & 3;
    int p    = (t >> 8) % 3;
    int kk   = t / 768;
    const float* W = (p == 0) ? Wq : ((p == 1) ? Wk : Wv);
    int n  = tile * 16 + (lane & 15);
    int k0 = kk * 32 + (lane >> 4) * 8;
    f16x8 frag;
#pragma unroll
    for (int j = 0; j < 8; ++j) frag[j] = (f16)W[(k0 + j) * HH + n];
    ((f16x8*)wf)[t] = frag;
}

static __device__ __forceinline__ f16x8 cvt8(float4 f0, float4 f1) {
    f16x8 h;
    h[0]=(f16)f0.x; h[1]=(f16)f0.y; h[2]=(f16)f0.z; h[3]=(f16)f0.w;
    h[4]=(f16)f1.x; h[5]=(f16)f1.y; h[6]=(f16)f1.z; h[7]=(f16)f1.w;
    return h;
}

__launch_bounds__(256, 4)   // VGPR<=128; LDS 27648 B
__global__ void attn_head(const float* __restrict__ x,
                          const f16* __restrict__ wf,
                          float* __restrict__ out) {
    // 27648 B: 3 tail arenas only. NO W staging in LDS — W-frags (147 KB total,
    // 12 KB per k-step, identical across waves AND blocks) are read straight
    // from global: L1/L2-resident broadcast. Projection loop has ZERO barriers.
    __shared__ __align__(16) char smem[3 * TT * LDP * sizeof(f16)];
    f16* qs   = (f16*)smem;
    f16* ksm  = qs + ARENA;
    f16* vst  = qs + 2 * ARENA;          // v transposed: vst[h][t]
    f16* ps   = qs;                      // overlays qs: own-wave rows only (safe, see S-phase)
    float* ost = (float*)smem;

    const int b    = blockIdx.x;
    const int tid  = threadIdx.x;
    const int wave = tid >> 6;
    const int lane = tid & 63;
    const int quad = lane >> 4;
    const int cl   = lane & 15;
    const int row0 = wave * 16;

    const floatx4 fzero = {0.f, 0.f, 0.f, 0.f};
    floatx4 acc[12];
#pragma unroll
    for (int T = 0; T < 12; ++T) acc[T] = fzero;

    // lane's x A-frag source: row row0+cl, col octet quad (m = lane&15, k = quad*8+j)
    const float* xp = x + ((size_t)b * TT + row0 + cl) * CDIM + quad * 8;
    // lane's W B-frag stream: frag (kk, T) at f16x8 index (kk*12 + T)*64 + lane
    const f16x8* wl = (const f16x8*)wf + lane;

    float4 xa = *(const float4*)(xp);
    float4 xb = *(const float4*)(xp + 4);

#pragma unroll 2
    for (int kk = 0; kk < NKK; ++kk) {
        f16x8 xf = cvt8(xa, xb);
        if (kk + 1 < NKK) {              // prefetch next x (HBM) under this iter's MFMAs
            xa = *(const float4*)(xp + (kk + 1) * 32);
            xb = *(const float4*)(xp + (kk + 1) * 32 + 4);
        }
        const f16x8* wk = wl + kk * 768;  // 12 tiles * 64 lanes
#pragma unroll
        for (int T = 0; T < 12; ++T) {   // B-frags straight from L1/L2 (hot 12 KB set)
            f16x8 bf = wk[T * 64];
            acc[T] = __builtin_amdgcn_mfma_f32_16x16x32_f16(xf, bf, acc[T], 0, 0, 0);
        }
    }

    // ---- spill q (pre-scaled), k (row-major [t][h]) and v (transposed [h][t]) ----
    // LDS is untouched so far: no barrier needed before the spill (disjoint writes).
    // C/D layout: col = (T&3)*16 + cl, row = row0 + quad*4 + r   [m89-verified]
#pragma unroll
    for (int T = 0; T < 12; ++T) {
        int p = T >> 2;
        int h = (T & 3) * 16 + cl;
        if (p == 2) {
            f16x4 vv;
            vv[0]=(f16)acc[T][0]; vv[1]=(f16)acc[T][1];
            vv[2]=(f16)acc[T][2]; vv[3]=(f16)acc[T][3];
            *(f16x4*)&vst[h * LDP + row0 + quad * 4] = vv;
        } else if (p == 0) {             // q: fold in SCALE here
#pragma unroll
            for (int r = 0; r < 4; ++r)
                qs[(row0 + quad * 4 + r) * LDP + h] = (f16)(acc[T][r] * SCALE);
        } else {
#pragma unroll
            for (int r = 0; r < 4; ++r)
                ksm[(row0 + quad * 4 + r) * LDP + h] = (f16)acc[T][r];
        }
    }
    __syncthreads();                     // barrier A: ksm/vst (cross-wave reads) published

    // ---- S = (q*SCALE) k^T  (wave w owns score rows row0..row0+15) ----
    // qs reads are OWN-wave rows only (row0+cl); ksm reads are cross-wave (barrier A).
    floatx4 sa[4];
#pragma unroll
    for (int t = 0; t < 4; ++t) sa[t] = fzero;
#pragma unroll
    for (int kv = 0; kv < 2; ++kv) {
        f16x8 aq = *(const f16x8*)&qs[(row0 + cl) * LDP + kv * 32 + quad * 8];
#pragma unroll
        for (int t = 0; t < 4; ++t) {
            f16x8 bk = *(const f16x8*)&ksm[(t * 16 + cl) * LDP + kv * 32 + quad * 8];
            sa[t] = __builtin_amdgcn_mfma_f32_16x16x32_f16(aq, bk, sa[t], 0, 0, 0);
        }
    }

    // ---- P = exp(S) masked, UNNORMALIZED. ps overlays qs but ONLY this wave's
    //      own 16 rows, which no other wave ever reads -> no barrier needed.
#pragma unroll
    for (int t = 0; t < 4; ++t) {
        int s = t * 16 + cl;
#pragma unroll
        for (int r = 0; r < 4; ++r) {
            int tr = row0 + quad * 4 + r;
            float p = (s <= tr) ? __expf(sa[t][r]) : 0.0f;
            ps[tr * LDP + s] = (f16)p;
        }
    }

    // ---- O_unnorm = P V ; den = P * ones. ps reads are own-wave rows (in-order
    //      DS pipe + compiler lgkm waits); vst reads stable since barrier A.
    floatx4 oa[4];
    floatx4 den = fzero;
#pragma unroll
    for (int t = 0; t < 4; ++t) oa[t] = fzero;
    f16x8 ones;
#pragma unroll
    for (int j = 0; j < 8; ++j) ones[j] = (f16)1.0f;
#pragma unroll
    for (int kv = 0; kv < 2; ++kv) {
        f16x8 ap = *(const f16x8*)&ps[(row0 + cl) * LDP + kv * 32 + quad * 8];
        den = __builtin_amdgcn_mfma_f32_16x16x32_f16(ap, ones, den, 0, 0, 0);
#pragma unroll
        for (int t = 0; t < 4; ++t) {
            f16x8 bv = *(const f16x8*)&vst[(t * 16 + cl) * LDP + kv * 32 + quad * 8];
            oa[t] = __builtin_amdgcn_mfma_f32_16x16x32_f16(ap, bv, oa[t], 0, 0, 0);
        }
    }
    float rden[4];
#pragma unroll
    for (int r = 0; r < 4; ++r) rden[r] = 1.0f / den[r];
    __syncthreads();                     // barrier E: all ps/vst reads done -> ost overlay safe

    // ---- O through LDS (ost spans the arena across wave boundaries) ----
#pragma unroll
    for (int t = 0; t < 4; ++t)
#pragma unroll
        for (int r = 0; r < 4; ++r)
            ost[(row0 + quad * 4 + r) * OST + t * 16 + cl] = oa[t][r] * rden[r];
    __syncthreads();                     // barrier C: ost published for cross-wave store

    float* op = out + (size_t)b * TT * HH;
#pragma unroll
    for (int i = 0; i < 4; ++i) {
        int row = i * 16 + (tid >> 4);
        int c4  = (tid & 15) * 4;
        floatx2 lo = *(const floatx2*)&ost[row * OST + c4];
        floatx2 hi = *(const floatx2*)&ost[row * OST + c4 + 2];
        float4 v; v.x = lo[0]; v.y = lo[1]; v.z = hi[0]; v.w = hi[1];
        *(float4*)&op[row * HH + c4] = v;   // 1 KB contiguous per wave-instruction
    }
}

extern "C" void kernel_launch(void* const* d_in, const int* in_sizes, int n_in,
                              void* d_out, int out_size, void* d_ws, size_t ws_size,
                              hipStream_t stream) {
    const float* x  = (const float*)d_in[0];
    const float* Wq = (const float*)d_in[1];
    const float* Wk = (const float*)d_in[2];
    const float* Wv = (const float*)d_in[3];
    float* out = (float*)d_out;
    f16* wf = (f16*)d_ws;   // needs 3*12*4*64*16 = 147456 bytes

    prep_w<<<36, 256, 0, stream>>>(Wq, Wk, Wv, wf);
    attn_head<<<2048, 256, 0, stream>>>(x, wf, out);
}

// Round 4
// 329.104 us; speedup vs baseline: 1.0052x; 1.0052x over previous
//
#include <hip/hip_runtime.h>
#include <stdint.h>

typedef _Float16 f16;
typedef _Float16 f16x8 __attribute__((ext_vector_type(8)));
typedef _Float16 f16x4 __attribute__((ext_vector_type(4)));
typedef float floatx4 __attribute__((ext_vector_type(4)));

#define TT 64
#define CDIM 384
#define HH 64
#define NKK 12          // CDIM/32 k-steps
#define LDP 72          // f16 LDS row stride for the P bounce
#define CHUNK 12288     // bytes per W k-chunk: 12 tiles * 64 lanes * 16 B
#define WBUFH 6144      // f16 elements per W buffer half (CHUNK/2)
#define SCALE 0.05103103630798288f   // 384^-0.5 (reference scales by C^-0.5)

// workspace byte offsets (ws >= ~51 MB; harness provides much more)
#define WF_OFF 0
#define QF_OFF (256 * 1024)
#define TENB   (2048 * 64 * 64 * 2)   // 16.78 MB per f16 tensor
#define KF_OFF (QF_OFF + TENB)
#define VT_OFF (KF_OFF + TENB)

// Pre-pass: Wq/Wk/Wv -> fp16 in exact MFMA B-fragment order:
// wf layout [kk][p][tile][lane] of f16x8; lane holds W[k=kk*32+quad*8+j][n=tile*16+(lane&15)]
__global__ void prep_w(const float* __restrict__ Wq,
                       const float* __restrict__ Wk,
                       const float* __restrict__ Wv,
                       f16* __restrict__ wf) {
    int t = blockIdx.x * 256 + threadIdx.x;
    if (t >= 3 * NKK * 4 * 64) return;
    int lane = t & 63;
    int tile = (t >> 6) & 3;
    int p    = (t >> 8) % 3;
    int kk   = t / 768;
    const float* W = (p == 0) ? Wq : ((p == 1) ? Wk : Wv);
    int n  = tile * 16 + (lane & 15);
    int k0 = kk * 32 + (lane >> 4) * 8;
    f16x8 frag;
#pragma unroll
    for (int j = 0; j < 8; ++j) frag[j] = (f16)W[(k0 + j) * HH + n];
    ((f16x8*)wf)[t] = frag;
}

static __device__ __forceinline__ f16x8 cvt8(float4 f0, float4 f1) {
    f16x8 h;
    h[0]=(f16)f0.x; h[1]=(f16)f0.y; h[2]=(f16)f0.z; h[3]=(f16)f0.w;
    h[4]=(f16)f1.x; h[5]=(f16)f1.y; h[6]=(f16)f1.z; h[7]=(f16)f1.w;
    return h;
}

// async global->LDS DMA, 16 B per lane; LDS dest = wave-uniform base + lane*16
static __device__ __forceinline__ void glds16(const void* g, void* l) {
    __builtin_amdgcn_global_load_lds(
        (const __attribute__((address_space(1))) uint32_t*)g,
        (__attribute__((address_space(3))) uint32_t*)l, 16, 0, 0);
}

// ---------------- Kernel 1: qkv projection GEMM ----------------
// [131072 x 384] @ [384 x 192], 128 rows/block (2 batches), 1024 blocks.
// Wave w owns rows R0 = bid*128 + w*32 .. +31 (2 m-tiles): 24 MFMA per 12
// B-frag ds_reads (2x amortization vs the old fused kernel). W staged via
// the verified counted-vmcnt double-buffer (never drains mid-loop).
// Outputs written DIRECTLY to global f16 (no spill barriers): q pre-scaled,
// k row-major [t][h], v transposed [h][t] per batch. 2B stores merge in L2.
__launch_bounds__(256, 3)
__global__ void proj_qkv(const float* __restrict__ x,
                         const f16* __restrict__ wf,
                         f16* __restrict__ qf,
                         f16* __restrict__ kf,
                         f16* __restrict__ vt) {
    __shared__ __align__(16) f16 wbuf[2 * WBUFH];   // 24576 B

    const int tid  = threadIdx.x;
    const int wave = tid >> 6;
    const int lane = tid & 63;
    const int quad = lane >> 4;
    const int cl   = lane & 15;
    const int R0   = blockIdx.x * 128 + wave * 32;

    const floatx4 fzero = {0.f, 0.f, 0.f, 0.f};
    floatx4 acc[2][12];
#pragma unroll
    for (int mi = 0; mi < 2; ++mi)
#pragma unroll
        for (int T = 0; T < 12; ++T) acc[mi][T] = fzero;

    const float* xp0 = x + (size_t)(R0 + cl) * CDIM + quad * 8;
    const float* xp1 = x + (size_t)(R0 + 16 + cl) * CDIM + quad * 8;
    const char*  wb  = (const char*)wf;
    const int lslot  = (wave * 64 + lane) * 16;

    // prologue: DMA chunk 0 {3 ops}, then x(0) {4 ops}; order pinned.
    float4 xa[2][2], xb[2][2];
#pragma unroll
    for (int j = 0; j < 3; ++j)
        glds16(wb + j * 4096 + lslot, wbuf + j * 2048 + wave * 512);
    asm volatile("" ::: "memory");
    xa[0][0] = *(const float4*)(xp0); xb[0][0] = *(const float4*)(xp0 + 4);
    xa[0][1] = *(const float4*)(xp1); xb[0][1] = *(const float4*)(xp1 + 4);
    asm volatile("" ::: "memory");

    // main loop: at top of iter kk, outstanding = [DMA(kk){3}, x(kk){<=4}] or
    // steady [DMA(kk){3}, x(kk+1-in-flight)]: vmcnt(4) retires DMA(kk),
    // leaves the 4 newest (next x) in flight. Uniform across all iters.
#pragma unroll
    for (int kk = 0; kk < NKK; ++kk) {
        asm volatile("s_waitcnt vmcnt(4)" ::: "memory");
        __builtin_amdgcn_s_barrier();     // publish chunk kk; prev readers done
        if (kk + 1 < NKK) {
            const int nb = (kk + 1) & 1;
#pragma unroll
            for (int j = 0; j < 3; ++j)
                glds16(wb + (kk + 1) * CHUNK + j * 4096 + lslot,
                       wbuf + nb * WBUFH + j * 2048 + wave * 512);
            asm volatile("" ::: "memory");
            xa[nb][0] = *(const float4*)(xp0 + (kk + 1) * 32);
            xb[nb][0] = *(const float4*)(xp0 + (kk + 1) * 32 + 4);
            xa[nb][1] = *(const float4*)(xp1 + (kk + 1) * 32);
            xb[nb][1] = *(const float4*)(xp1 + (kk + 1) * 32 + 4);
            asm volatile("" ::: "memory");
        }
        const int cur = kk & 1;
        f16x8 xf0 = cvt8(xa[cur][0], xb[cur][0]);   // reg-dep waits handled by compiler
        f16x8 xf1 = cvt8(xa[cur][1], xb[cur][1]);
        const f16* wc = wbuf + cur * WBUFH;
        __builtin_amdgcn_s_setprio(1);
#pragma unroll
        for (int T = 0; T < 12; ++T) {
            f16x8 bf = *(const f16x8*)&wc[(T * 64 + lane) * 8];
            acc[0][T] = __builtin_amdgcn_mfma_f32_16x16x32_f16(xf0, bf, acc[0][T], 0, 0, 0);
            acc[1][T] = __builtin_amdgcn_mfma_f32_16x16x32_f16(xf1, bf, acc[1][T], 0, 0, 0);
        }
        __builtin_amdgcn_s_setprio(0);
    }

    // epilogue: direct global stores. C/D layout: col h=(T&3)*16+cl,
    // row = R0 + mi*16 + quad*4 + r   [m89-verified]
#pragma unroll
    for (int mi = 0; mi < 2; ++mi) {
        const int rbase = R0 + mi * 16 + quad * 4;
#pragma unroll
        for (int T = 0; T < 12; ++T) {
            const int p = T >> 2;
            const int h = (T & 3) * 16 + cl;
            if (p == 0) {
#pragma unroll
                for (int r = 0; r < 4; ++r)
                    qf[(size_t)(rbase + r) * HH + h] = (f16)(acc[mi][T][r] * SCALE);
            } else if (p == 1) {
#pragma unroll
                for (int r = 0; r < 4; ++r)
                    kf[(size_t)(rbase + r) * HH + h] = (f16)acc[mi][T][r];
            } else {                       // v transposed: vt[b][h][t], f16x4 in t
                const int tb = R0 + mi * 16;          // batch-aligned (mult of 16)
                const int b  = tb >> 6;
                const int t0 = (tb & 63) + quad * 4;
                f16x4 vv;
                vv[0]=(f16)acc[mi][T][0]; vv[1]=(f16)acc[mi][T][1];
                vv[2]=(f16)acc[mi][T][2]; vv[3]=(f16)acc[mi][T][3];
                *(f16x4*)&vt[(size_t)b * 4096 + h * 64 + t0] = vv;
            }
        }
    }
}

// ---------------- Kernel 2: per-batch attention ----------------
// One block per batch, 4 independent waves (ZERO barriers), wave w owns
// score rows w*16..+15. All operands register-resident; P bounced through
// own-wave LDS rows only (verified in-order DS pattern from R3).
__launch_bounds__(256, 4)
__global__ void attn_sm(const f16* __restrict__ qf,
                        const f16* __restrict__ kf,
                        const f16* __restrict__ vt,
                        float* __restrict__ out) {
    __shared__ __align__(16) f16 ps[TT * LDP];   // 9216 B

    const int b    = blockIdx.x;
    const int tid  = threadIdx.x;
    const int wave = tid >> 6;
    const int lane = tid & 63;
    const int quad = lane >> 4;
    const int cl   = lane & 15;
    const int row0 = wave * 16;
    const size_t base = (size_t)b * (TT * HH);

    // issue ALL frag loads upfront: one latency window, 18 independent 16B loads
    f16x8 aq[2], bk[4][2], bv[4][2];
#pragma unroll
    for (int kv = 0; kv < 2; ++kv) {
        aq[kv] = *(const f16x8*)&qf[base + (row0 + cl) * HH + kv * 32 + quad * 8];
#pragma unroll
        for (int t = 0; t < 4; ++t) {
            bk[t][kv] = *(const f16x8*)&kf[base + (t * 16 + cl) * HH + kv * 32 + quad * 8];
            bv[t][kv] = *(const f16x8*)&vt[base + (t * 16 + cl) * HH + kv * 32 + quad * 8];
        }
    }

    const floatx4 fzero = {0.f, 0.f, 0.f, 0.f};
    floatx4 sa[4];
#pragma unroll
    for (int t = 0; t < 4; ++t) sa[t] = fzero;
#pragma unroll
    for (int kv = 0; kv < 2; ++kv)
#pragma unroll
        for (int t = 0; t < 4; ++t)
            sa[t] = __builtin_amdgcn_mfma_f32_16x16x32_f16(aq[kv], bk[t][kv], sa[t], 0, 0, 0);

    // P = exp(S) masked, UNNORMALIZED (scores ~N(0,0.41^2); den via ones-MFMA)
#pragma unroll
    for (int t = 0; t < 4; ++t) {
        int s = t * 16 + cl;
#pragma unroll
        for (int r = 0; r < 4; ++r) {
            int tr = row0 + quad * 4 + r;
            float p = (s <= tr) ? __expf(sa[t][r]) : 0.0f;
            ps[tr * LDP + s] = (f16)p;
        }
    }

    floatx4 oa[4];
    floatx4 den = fzero;
#pragma unroll
    for (int t = 0; t < 4; ++t) oa[t] = fzero;
    f16x8 ones;
#pragma unroll
    for (int j = 0; j < 8; ++j) ones[j] = (f16)1.0f;
#pragma unroll
    for (int kv = 0; kv < 2; ++kv) {
        f16x8 ap = *(const f16x8*)&ps[(row0 + cl) * LDP + kv * 32 + quad * 8];
        den = __builtin_amdgcn_mfma_f32_16x16x32_f16(ap, ones, den, 0, 0, 0);
#pragma unroll
        for (int t = 0; t < 4; ++t)
            oa[t] = __builtin_amdgcn_mfma_f32_16x16x32_f16(ap, bv[t][kv], oa[t], 0, 0, 0);
    }
    float rden[4];
#pragma unroll
    for (int r = 0; r < 4; ++r) rden[r] = 1.0f / den[r];

    // direct stores: 4B/lane, 16 consecutive lanes -> 64B chunks, merge in L2
    float* op = out + base;
#pragma unroll
    for (int t = 0; t < 4; ++t)
#pragma unroll
        for (int r = 0; r < 4; ++r)
            op[(row0 + quad * 4 + r) * HH + t * 16 + cl] = oa[t][r] * rden[r];
}

extern "C" void kernel_launch(void* const* d_in, const int* in_sizes, int n_in,
                              void* d_out, int out_size, void* d_ws, size_t ws_size,
                              hipStream_t stream) {
    const float* x  = (const float*)d_in[0];
    const float* Wq = (const float*)d_in[1];
    const float* Wk = (const float*)d_in[2];
    const float* Wv = (const float*)d_in[3];
    float* out = (float*)d_out;
    char* ws = (char*)d_ws;
    f16* wf = (f16*)(ws + WF_OFF);
    f16* qf = (f16*)(ws + QF_OFF);
    f16* kf = (f16*)(ws + KF_OFF);
    f16* vt = (f16*)(ws + VT_OFF);

    prep_w<<<36, 256, 0, stream>>>(Wq, Wk, Wv, wf);
    proj_qkv<<<1024, 256, 0, stream>>>(x, wf, qf, kf, vt);
    attn_sm<<<2048, 256, 0, stream>>>(qf, kf, vt, out);
}

// Round 5
// 295.842 us; speedup vs baseline: 1.1182x; 1.1124x over previous
//
#include <hip/hip_runtime.h>
#include <stdint.h>

typedef _Float16 f16;
typedef _Float16 f16x8 __attribute__((ext_vector_type(8)));
typedef _Float16 f16x4 __attribute__((ext_vector_type(4)));
typedef float floatx4 __attribute__((ext_vector_type(4)));
typedef float floatx2 __attribute__((ext_vector_type(2)));

#define TT 64
#define CDIM 384
#define HH 64
#define NK2 6           // CDIM/64 double-k-steps
#define LDP 72          // f16 LDS row stride for q/k/v/p tiles
#define OST 66          // fp32 O-staging row stride
#define CHUNK2 24576    // bytes per BK=64 W chunk (2 old chunks)
#define C2H 12288       // f16 elems per BK=64 chunk
#define ARENA 4608      // f16 elems per tail arena (64*LDP)
#define SCALE 0.05103103630798288f   // 384^-0.5 (reference scales by C^-0.5)

// Pre-pass: Wq/Wk/Wv -> fp16 in exact MFMA B-fragment order:
// wf layout [kk][p][tile][lane] of f16x8; lane holds W[k=kk*32+quad*8+j][n=tile*16+(lane&15)]
__global__ void prep_w(const float* __restrict__ Wq,
                       const float* __restrict__ Wk,
                       const float* __restrict__ Wv,
                       f16* __restrict__ wf) {
    int t = blockIdx.x * 256 + threadIdx.x;
    if (t >= 3 * 12 * 4 * 64) return;
    int lane = t & 63;
    int tile = (t >> 6) & 3;
    int p    = (t >> 8) % 3;
    int kk   = t / 768;
    const float* W = (p == 0) ? Wq : ((p == 1) ? Wk : Wv);
    int n  = tile * 16 + (lane & 15);
    int k0 = kk * 32 + (lane >> 4) * 8;
    f16x8 frag;
#pragma unroll
    for (int j = 0; j < 8; ++j) frag[j] = (f16)W[(k0 + j) * HH + n];
    ((f16x8*)wf)[t] = frag;
}

static __device__ __forceinline__ f16x8 cvt8(float4 f0, float4 f1) {
    f16x8 h;
    h[0]=(f16)f0.x; h[1]=(f16)f0.y; h[2]=(f16)f0.z; h[3]=(f16)f0.w;
    h[4]=(f16)f1.x; h[5]=(f16)f1.y; h[6]=(f16)f1.z; h[7]=(f16)f1.w;
    return h;
}

// async global->LDS DMA, 16 B per lane; LDS dest = wave-uniform base + lane*16
static __device__ __forceinline__ void glds16(const void* g, void* l) {
    __builtin_amdgcn_global_load_lds(
        (const __attribute__((address_space(1))) uint32_t*)g,
        (__attribute__((address_space(3))) uint32_t*)l, 16, 0, 0);
}

// 512 threads / 8 waves / 2 batches per block. Wave w owns 16 rows
// (m-tile w of the 128-row block). BK=64 projection: 6 barriers not 12,
// 4 KB/wave of x in flight. LDS 55296 B -> 2 blocks/CU (16 waves/CU).
__launch_bounds__(512, 4)
__global__ void attn_head(const float* __restrict__ x,
                          const f16* __restrict__ wf,
                          float* __restrict__ out) {
    // arenas: [qsA ksmA vstA qsB ksmB vstB] x 4608 f16 = 55296 B.
    // W double buffer (2*24576 = 49152 B) overlays the front during projection.
    __shared__ __align__(16) char smem[6 * ARENA * sizeof(f16)];
    f16* wbuf = (f16*)smem;

    const int b0   = blockIdx.x * 2;
    const int tid  = threadIdx.x;
    const int wave = tid >> 6;        // 0..7
    const int lane = tid & 63;
    const int quad = lane >> 4;
    const int cl   = lane & 15;
    const int bb   = wave >> 2;       // batch half 0/1
    const int row0b = (wave & 3) * 16;   // row within the batch

    const floatx4 fzero = {0.f, 0.f, 0.f, 0.f};
    floatx4 acc[12];
#pragma unroll
    for (int T = 0; T < 12; ++T) acc[T] = fzero;

    // lane's x A-frag source: global row bid*128 + wave*16 + cl
    const float* xp = x + ((size_t)blockIdx.x * 128 + wave * 16 + cl) * CDIM + quad * 8;
    const char* wb  = (const char*)wf;

    // ---- prologue: DMA chunk 0 {3 ops}, then x(0) {4 ops}; order pinned ----
    float4 xa[2][2], xb[2][2];
#pragma unroll
    for (int j = 0; j < 3; ++j)
        glds16(wb + j * 8192 + tid * 16, wbuf + j * 4096 + wave * 512);
    asm volatile("" ::: "memory");
#pragma unroll
    for (int s = 0; s < 2; ++s) {
        xa[0][s] = *(const float4*)(xp + s * 32);
        xb[0][s] = *(const float4*)(xp + s * 32 + 4);
    }
    asm volatile("" ::: "memory");

    // ---- main loop: BK=64, counted vmcnt. At top of iter kk outstanding =
    //      [DMA(kk){3}, x(kk){4}] -> vmcnt(4) retires exactly DMA(kk).
#pragma unroll
    for (int kk = 0; kk < NK2; ++kk) {
        asm volatile("s_waitcnt vmcnt(4)" ::: "memory");
        __builtin_amdgcn_s_barrier();     // chunk kk published; other buf free
        if (kk + 1 < NK2) {
            const int nb = (kk + 1) & 1;
#pragma unroll
            for (int j = 0; j < 3; ++j)
                glds16(wb + (kk + 1) * CHUNK2 + j * 8192 + tid * 16,
                       wbuf + nb * C2H + j * 4096 + wave * 512);
            asm volatile("" ::: "memory");
#pragma unroll
            for (int s = 0; s < 2; ++s) {
                xa[nb][s] = *(const float4*)(xp + (kk + 1) * 64 + s * 32);
                xb[nb][s] = *(const float4*)(xp + (kk + 1) * 64 + s * 32 + 4);
            }
            asm volatile("" ::: "memory");
        }
        const int cur = kk & 1;
        const f16* wc = wbuf + cur * C2H;
        f16x8 xf0 = cvt8(xa[cur][0], xb[cur][0]);   // reg-dep waits: precise vmcnt(N)
        f16x8 xf1 = cvt8(xa[cur][1], xb[cur][1]);
        __builtin_amdgcn_s_setprio(1);
#pragma unroll
        for (int T = 0; T < 12; ++T) {
            f16x8 bf0 = *(const f16x8*)&wc[(T * 64 + lane) * 8];
            acc[T] = __builtin_amdgcn_mfma_f32_16x16x32_f16(xf0, bf0, acc[T], 0, 0, 0);
        }
#pragma unroll
        for (int T = 0; T < 12; ++T) {
            f16x8 bf1 = *(const f16x8*)&wc[6144 + (T * 64 + lane) * 8];
            acc[T] = __builtin_amdgcn_mfma_f32_16x16x32_f16(xf1, bf1, acc[T], 0, 0, 0);
        }
        __builtin_amdgcn_s_setprio(0);
    }
    __syncthreads();                     // barrier D: W reads retired -> arena overlay safe

    // ---- spill into this batch's arenas (q pre-scaled, k [t][h], v^T [h][t]) ----
    // C/D layout: col = (T&3)*16 + cl, row = row0b + quad*4 + r   [m89-verified]
    f16* qs  = (f16*)smem + bb * 3 * ARENA;
    f16* ksm = qs + ARENA;
    f16* vst = qs + 2 * ARENA;
    f16* ps  = qs;                       // overlays qs: own-wave rows only
#pragma unroll
    for (int T = 0; T < 12; ++T) {
        int p = T >> 2;
        int h = (T & 3) * 16 + cl;
        if (p == 2) {
            f16x4 vv;
            vv[0]=(f16)acc[T][0]; vv[1]=(f16)acc[T][1];
            vv[2]=(f16)acc[T][2]; vv[3]=(f16)acc[T][3];
            *(f16x4*)&vst[h * LDP + row0b + quad * 4] = vv;
        } else if (p == 0) {             // q: fold in SCALE here
#pragma unroll
            for (int r = 0; r < 4; ++r)
                qs[(row0b + quad * 4 + r) * LDP + h] = (f16)(acc[T][r] * SCALE);
        } else {
#pragma unroll
            for (int r = 0; r < 4; ++r)
                ksm[(row0b + quad * 4 + r) * LDP + h] = (f16)acc[T][r];
        }
    }
    __syncthreads();                     // barrier A: ksm/vst published (cross-wave in batch)

    // ---- S = (q*SCALE) k^T  (wave owns score rows row0b..row0b+15 of its batch) ----
    floatx4 sa[4];
#pragma unroll
    for (int t = 0; t < 4; ++t) sa[t] = fzero;
#pragma unroll
    for (int kv = 0; kv < 2; ++kv) {
        f16x8 aq = *(const f16x8*)&qs[(row0b + cl) * LDP + kv * 32 + quad * 8];
#pragma unroll
        for (int t = 0; t < 4; ++t) {
            f16x8 bk = *(const f16x8*)&ksm[(t * 16 + cl) * LDP + kv * 32 + quad * 8];
            sa[t] = __builtin_amdgcn_mfma_f32_16x16x32_f16(aq, bk, sa[t], 0, 0, 0);
        }
    }

    // ---- P = exp(S) masked, UNNORMALIZED; ps overlays qs own-wave rows only ----
#pragma unroll
    for (int t = 0; t < 4; ++t) {
        int s = t * 16 + cl;
#pragma unroll
        for (int r = 0; r < 4; ++r) {
            int tr = row0b + quad * 4 + r;
            float p = (s <= tr) ? __expf(sa[t][r]) : 0.0f;
            ps[tr * LDP + s] = (f16)p;
        }
    }

    // ---- O_unnorm = P V ; den = P * ones (own-row ps reads: in-order DS pipe) ----
    floatx4 oa[4];
    floatx4 den = fzero;
#pragma unroll
    for (int t = 0; t < 4; ++t) oa[t] = fzero;
    f16x8 ones;
#pragma unroll
    for (int j = 0; j < 8; ++j) ones[j] = (f16)1.0f;
#pragma unroll
    for (int kv = 0; kv < 2; ++kv) {
        f16x8 ap = *(const f16x8*)&ps[(row0b + cl) * LDP + kv * 32 + quad * 8];
        den = __builtin_amdgcn_mfma_f32_16x16x32_f16(ap, ones, den, 0, 0, 0);
#pragma unroll
        for (int t = 0; t < 4; ++t) {
            f16x8 bv = *(const f16x8*)&vst[(t * 16 + cl) * LDP + kv * 32 + quad * 8];
            oa[t] = __builtin_amdgcn_mfma_f32_16x16x32_f16(ap, bv, oa[t], 0, 0, 0);
        }
    }
    float rden[4];
#pragma unroll
    for (int r = 0; r < 4; ++r) rden[r] = 1.0f / den[r];
    __syncthreads();                     // barrier E: ps/vst reads done -> ost overlay safe

    // ---- O through LDS (per-batch fp32 staging) ----
    float* ost = (float*)smem + bb * (TT * OST);
#pragma unroll
    for (int t = 0; t < 4; ++t)
#pragma unroll
        for (int r = 0; r < 4; ++r)
            ost[(row0b + quad * 4 + r) * OST + t * 16 + cl] = oa[t][r] * rden[r];
    __syncthreads();                     // barrier C: ost published

    // ---- store: threads 0-255 -> batch b0, 256-511 -> batch b0+1 ----
    const int sb   = tid >> 8;
    const int tid2 = tid & 255;
    const float* osb = (const float*)smem + sb * (TT * OST);
    float* op = out + ((size_t)b0 + sb) * TT * HH;
#pragma unroll
    for (int i = 0; i < 4; ++i) {
        int row = i * 16 + (tid2 >> 4);
        int c4  = (tid2 & 15) * 4;
        floatx2 lo = *(const floatx2*)&osb[row * OST + c4];
        floatx2 hi = *(const floatx2*)&osb[row * OST + c4 + 2];
        float4 v; v.x = lo[0]; v.y = lo[1]; v.z = hi[0]; v.w = hi[1];
        *(float4*)&op[row * HH + c4] = v;
    }
}

extern "C" void kernel_launch(void* const* d_in, const int* in_sizes, int n_in,
                              void* d_out, int out_size, void* d_ws, size_t ws_size,
                              hipStream_t stream) {
    const float* x  = (const float*)d_in[0];
    const float* Wq = (const float*)d_in[1];
    const float* Wk = (const float*)d_in[2];
    const float* Wv = (const float*)d_in[3];
    float* out = (float*)d_out;
    f16* wf = (f16*)d_ws;   // 3*12*4*64*16 = 147456 bytes

    prep_w<<<36, 256, 0, stream>>>(Wq, Wk, Wv, wf);
    attn_head<<<1024, 512, 0, stream>>>(x, wf, out);
}